// Round 12
// baseline (434.464 us; speedup 1.0000x reference)
//
#include <hip/hip_runtime.h>
#include <math.h>

// Problem constants (match reference)
#define NN    4096
#define EE    131072
#define ENE   (EE + NN)      // edges + self loops = 135168
#define IND   128
#define HH    8
#define HIDC  64
#define DD    512
#define D3    1536
#define DFF2  256

typedef __attribute__((ext_vector_type(8))) short short8;
typedef __attribute__((ext_vector_type(4))) float f32x4;
typedef __attribute__((ext_vector_type(2))) unsigned int uint2v;

__device__ __forceinline__ float lrelu02(float x) { return x >= 0.f ? x : 0.2f * x; }

// round-to-nearest-even f32 -> bf16 bits (inputs finite)
__device__ __forceinline__ unsigned short f2bf(float x) {
    unsigned int u = __float_as_uint(x);
    u += 0x7fffu + ((u >> 16) & 1u);
    return (unsigned short)(u >> 16);
}
__device__ __forceinline__ float bf2f(unsigned short u) {
    return __uint_as_float((unsigned int)u << 16);
}
// packed RNE f32x2 -> bf16x2 (T12 recipe)
__device__ __forceinline__ unsigned int cvt_pk_bf16(float lo, float hi) {
    unsigned int r;
    asm("v_cvt_pk_bf16_f32 %0, %1, %2" : "=v"(r) : "v"(lo), "v"(hi));
    return r;
}
// 3-input max (T17)
__device__ __forceinline__ float max3f(float a, float b, float c) {
    float r;
    asm("v_max3_f32 %0, %1, %2, %3" : "=v"(r) : "v"(a), "v"(b), "v"(c));
    return r;
}

// ---------------------------------------------------------------------------
// Batched fp32 -> bf16 conversion (weights + x), one launch, 6 segments.
// ---------------------------------------------------------------------------
struct CvtJobs {
    const float* src[6];
    unsigned short* dst[6];
    int n[6];
};

__global__ __launch_bounds__(256) void cvt_many(CvtJobs jb, int total)
{
    int i = (blockIdx.x * 256 + threadIdx.x) * 4;
    if (i >= total) return;
    int s = 0;
    while (i >= jb.n[s]) { i -= jb.n[s]; ++s; }
    float4 v = *(const float4*)(jb.src[s] + i);
    unsigned int lo = (unsigned int)f2bf(v.x) | ((unsigned int)f2bf(v.y) << 16);
    unsigned int hi = (unsigned int)f2bf(v.z) | ((unsigned int)f2bf(v.w) << 16);
    uint2v pk; pk.x = lo; pk.y = hi;
    *(uint2v*)(jb.dst[s] + i) = pk;
}

// ---------------------------------------------------------------------------
// bf16 MFMA GEMM, 64x64 tile (grid-utilization per G11; handles all GEMMs).
// flags: bit0 = bf16 out, bit1 = relu, bit2 = scale cols<512 by 0.125*log2e.
// ---------------------------------------------------------------------------
__global__ __launch_bounds__(256) void gemm64(const unsigned short* __restrict__ A,
                                              const unsigned short* __restrict__ W,
                                              const float* __restrict__ bias,
                                              void* __restrict__ C,
                                              int M, int K, int N, int flags)
{
    __shared__ __align__(16) unsigned short As[64 * 64];
    __shared__ __align__(16) unsigned short Bs[64 * 64];

    const int t = threadIdx.x, lane = t & 63, w = t >> 6;
    const int wr = w >> 1, wc = w & 1;
    const int bm = blockIdx.y * 64, bn = blockIdx.x * 64;
    const int q = lane & 15, g = lane >> 4;

    f32x4 acc[2][2];
#pragma unroll
    for (int m = 0; m < 2; ++m)
#pragma unroll
        for (int n = 0; n < 2; ++n) acc[m][n] = (f32x4){0.f, 0.f, 0.f, 0.f};

    const int srow = t >> 2, sh = t & 3;
    const unsigned short* Ag = A + (size_t)(bm + srow) * K + sh * 16;
    const unsigned short* Wg = W + (size_t)(bn + srow) * K + sh * 16;
    int wofs[2];
#pragma unroll
    for (int i = 0; i < 2; ++i)
        wofs[i] = srow * 128 + ((((sh * 2 + i) * 16) ^ ((srow & 7) << 4)));

    for (int k0 = 0; k0 < K; k0 += 64) {
        short8 av[2], bv[2];
#pragma unroll
        for (int i = 0; i < 2; ++i) {
            av[i] = *(const short8*)(Ag + k0 + i * 8);
            bv[i] = *(const short8*)(Wg + k0 + i * 8);
        }
        __syncthreads();
#pragma unroll
        for (int i = 0; i < 2; ++i) {
            *(short8*)((char*)As + wofs[i]) = av[i];
            *(short8*)((char*)Bs + wofs[i]) = bv[i];
        }
        __syncthreads();

        short8 af[2][2], bfr[2][2];
#pragma unroll
        for (int m = 0; m < 2; ++m) {
            const int row = wr * 32 + m * 16 + q;
#pragma unroll
            for (int kk = 0; kk < 2; ++kk)
                af[kk][m] = *(const short8*)((const char*)As +
                    row * 128 + ((((kk * 4 + g) * 16) ^ ((row & 7) << 4))));
        }
#pragma unroll
        for (int n = 0; n < 2; ++n) {
            const int row = wc * 32 + n * 16 + q;
#pragma unroll
            for (int kk = 0; kk < 2; ++kk)
                bfr[kk][n] = *(const short8*)((const char*)Bs +
                    row * 128 + ((((kk * 4 + g) * 16) ^ ((row & 7) << 4))));
        }
#pragma unroll
        for (int kk = 0; kk < 2; ++kk)
#pragma unroll
            for (int m = 0; m < 2; ++m)
#pragma unroll
                for (int n = 0; n < 2; ++n)
                    acc[m][n] = __builtin_amdgcn_mfma_f32_16x16x32_bf16(
                        bfr[kk][n], af[kk][m], acc[m][n], 0, 0, 0);
    }

    const int obf = flags & 1, orelu = flags & 2, oqs = flags & 4;
#pragma unroll
    for (int m = 0; m < 2; ++m) {
        const int row = bm + wr * 32 + m * 16 + q;
#pragma unroll
        for (int n = 0; n < 2; ++n) {
            const int col0 = bn + wc * 32 + n * 16 + g * 4;
            f32x4 v = acc[m][n];
            if (bias) {
                float4 bv4 = *(const float4*)(bias + col0);
                v[0] += bv4.x; v[1] += bv4.y; v[2] += bv4.z; v[3] += bv4.w;
            }
            if (oqs && col0 < DD) {
                // 1/sqrt(64) * log2(e): attention runs softmax in exp2 domain
                const float qs = 0.18033688f;
                v[0] *= qs; v[1] *= qs; v[2] *= qs; v[3] *= qs;
            }
            if (orelu) {
                v[0] = fmaxf(v[0], 0.f); v[1] = fmaxf(v[1], 0.f);
                v[2] = fmaxf(v[2], 0.f); v[3] = fmaxf(v[3], 0.f);
            }
            if (obf) {
                uint2v pk;
                pk.x = (unsigned int)f2bf(v[0]) | ((unsigned int)f2bf(v[1]) << 16);
                pk.y = (unsigned int)f2bf(v[2]) | ((unsigned int)f2bf(v[3]) << 16);
                *(uint2v*)((unsigned short*)C + (size_t)row * N + col0) = pk;
            } else {
                float4 o; o.x = v[0]; o.y = v[1]; o.z = v[2]; o.w = v[3];
                *(float4*)((float*)C + (size_t)row * N + col0) = o;
            }
        }
    }
}

// ---------------------------------------------------------------------------
// a_src[n,h] = <hlin[n,h,:], att_src[h,:]>, same for dst. hlin is bf16.
// ---------------------------------------------------------------------------
__global__ void att_proj(const unsigned short* __restrict__ hlin,
                         const float* __restrict__ att_s,
                         const float* __restrict__ att_d,
                         float* __restrict__ a_src, float* __restrict__ a_dst)
{
    int idx = blockIdx.x * 256 + threadIdx.x;
    if (idx >= NN * HH) return;
    int n = idx >> 3, h = idx & 7;
    const unsigned short* hp = hlin + (size_t)n * DD + h * HIDC;
    const float* as = att_s + h * HIDC;
    const float* ad = att_d + h * HIDC;
    float s1 = 0.f, s2 = 0.f;
#pragma unroll 8
    for (int c = 0; c < HIDC; ++c) {
        float hv = bf2f(hp[c]);
        s1 += hv * as[c]; s2 += hv * ad[c];
    }
    a_src[idx] = s1;
    a_dst[idx] = s2;
}

// ---------------------------------------------------------------------------
// CSR build: histogram over dst (incl. self-loops), scan, scatter src indices.
// ---------------------------------------------------------------------------
__global__ void hist_kernel(const int* __restrict__ ei, int* __restrict__ counts)
{
    int i = blockIdx.x * 256 + threadIdx.x;
    if (i >= ENE) return;
    int dst = (i < EE) ? ei[EE + i] : (i - EE);
    atomicAdd(&counts[dst], 1);
}

__global__ __launch_bounds__(1024) void scan_kernel(const int* __restrict__ counts,
                                                    int* __restrict__ offsets)
{
    __shared__ int sums[1024];
    int t = threadIdx.x;
    int v0 = counts[t*4+0], v1 = counts[t*4+1], v2 = counts[t*4+2], v3 = counts[t*4+3];
    sums[t] = v0 + v1 + v2 + v3;
    __syncthreads();
    for (int off = 1; off < 1024; off <<= 1) {
        int x = (t >= off) ? sums[t - off] : 0;
        __syncthreads();
        sums[t] += x;
        __syncthreads();
    }
    int pre = (t > 0) ? sums[t-1] : 0;
    offsets[t*4+0] = pre;
    offsets[t*4+1] = pre + v0;
    offsets[t*4+2] = pre + v0 + v1;
    offsets[t*4+3] = pre + v0 + v1 + v2;
    if (t == 1023) offsets[4096] = sums[1023];
}

__global__ void scatter_kernel(const int* __restrict__ ei, const int* __restrict__ offs,
                               int* __restrict__ cursor, int* __restrict__ src_sorted)
{
    int i = blockIdx.x * 256 + threadIdx.x;
    if (i >= ENE) return;
    int s, d;
    if (i < EE) { s = ei[i]; d = ei[EE + i]; } else { s = d = i - EE; }
    int pos = atomicAdd(&cursor[d], 1);
    src_sorted[offs[d] + pos] = s;
}

// ---------------------------------------------------------------------------
// GAT aggregation: one block per dst node. hlin is bf16; writes fp32 + bf16.
// ---------------------------------------------------------------------------
__global__ __launch_bounds__(256) void gat_node(const unsigned short* __restrict__ hlin,
                                                const float* __restrict__ a_src,
                                                const float* __restrict__ a_dst,
                                                const int* __restrict__ offs,
                                                const int* __restrict__ src_sorted,
                                                const float* __restrict__ bias,
                                                float* __restrict__ out,
                                                unsigned short* __restrict__ outb)
{
    __shared__ float adst[8];
    __shared__ float emax[8];
    __shared__ float denom[8];
    __shared__ float red[256];
    __shared__ float p_lds[16][8];
    __shared__ int   srcs[16];

    const int n = blockIdx.x, t = threadIdx.x;
    if (t < 8) { adst[t] = a_dst[n * 8 + t]; denom[t] = 0.f; }
    const int off0 = offs[n];
    const int deg  = offs[n+1] - off0;
    __syncthreads();

    const int h = t & 7, slot = t >> 3;
    float mx = -3.0e38f;
    for (int j = slot; j < deg; j += 32) {
        int s = src_sorted[off0 + j];
        mx = fmaxf(mx, a_src[s * 8 + h] + adst[h]);
    }
    red[t] = mx;
    __syncthreads();
    for (int half = 128; half >= 8; half >>= 1) {
        if (t < half) red[t] = fmaxf(red[t], red[t + half]);
        __syncthreads();
    }
    if (t < 8) emax[t] = lrelu02(red[t]);
    __syncthreads();

    float acc0 = 0.f, acc1 = 0.f;
    const int h0 = t >> 6, h1 = (t + 256) >> 6;
    for (int base = 0; base < deg; base += 16) {
        int cnt = min(16, deg - base);
        if (t < cnt * 8) {
            int j = base + (t >> 3);
            int s = src_sorted[off0 + j];
            if ((t & 7) == 0) srcs[t >> 3] = s;
            float x = a_src[s * 8 + (t & 7)] + adst[t & 7];
            float p = __expf(lrelu02(x) - emax[t & 7]);
            p_lds[t >> 3][t & 7] = p;
            atomicAdd(&denom[t & 7], p);
        }
        __syncthreads();
        for (int jj = 0; jj < cnt; ++jj) {
            int s = srcs[jj];
            const unsigned short* hp = hlin + (size_t)s * DD;
            acc0 += p_lds[jj][h0] * bf2f(hp[t]);
            acc1 += p_lds[jj][h1] * bf2f(hp[256 + t]);
        }
        __syncthreads();
    }
    float o0 = acc0 / (denom[h0] + 1e-16f) + bias[t];
    float o1 = acc1 / (denom[h1] + 1e-16f) + bias[256 + t];
    out[(size_t)n * DD + t]        = o0;
    out[(size_t)n * DD + 256 + t]  = o1;
    outb[(size_t)n * DD + t]       = f2bf(o0);
    outb[(size_t)n * DD + 256 + t] = f2bf(o1);
}

// ---------------------------------------------------------------------------
// bf16 MFMA flash attention, v7: r9 base + T15 cross-tile pipeline. The next
// tile's QK^T MFMAs (K already resident via dbuf) are issued BEFORE the
// current tile's softmax+PV, breaking the serial QK->SM->PV chain (r11 audit:
// 6150 cy/tile vs ~4100 cy resource floor -> dependency-limited, no pipe
// saturated). Buffer rotation: tile kb writes kb+2 into the CURRENT buffer
// (K(kb)/V(kb) dead after QK(kb-1)/PV(kb)) with barrier-write-barrier.
// Two statically-named score sets st_a/st_b (rule #20), x2-unrolled loop.
// ---------------------------------------------------------------------------
#define KVB 128
#define NTT (NN / KVB)   // 32 tiles

__global__ __launch_bounds__(256) void attn_mfma(const unsigned short* __restrict__ qkv,
                                                 unsigned short* __restrict__ aob)
{
    __shared__ __align__(16) unsigned short Ks0[KVB * 64];
    __shared__ __align__(16) unsigned short Vt0[80 * KVB];   // rows 64..79: ones-block
    __shared__ __align__(16) unsigned short Ks1[KVB * 64];
    __shared__ __align__(16) unsigned short Vt1[80 * KVB];

    const int t = threadIdx.x;
    const int w = t >> 6, lane = t & 63;
    const int q15 = lane & 15, g = lane >> 4;

    // head-per-XCD: h = bid&7 pins each head's K/V (1MB) + Q to one XCD's L2.
    const int fid = blockIdx.x;
    const int h = fid & 7, qb = fid >> 3;
    const int qbase = qb * 64 + w * 16;

    // Q fragments (0.125*log2e pre-folded by QKV GEMM epilogue)
    const unsigned short* qrow = qkv + (size_t)(qbase + q15) * D3 + h * HIDC;
    const short8 qf0 = *(const short8*)(qrow + g * 8);
    const short8 qf1 = *(const short8*)(qrow + 32 + g * 8);

    f32x4 O[4];
#pragma unroll
    for (int db = 0; db < 4; ++db) O[db] = (f32x4){0.f, 0.f, 0.f, 0.f};
    f32x4 O5 = (f32x4){0.f, 0.f, 0.f, 0.f};     // ones-row block: O5[0] = l (lanes 0..15)
    float m_run = -3.0e38f;

    // ---- hoisted swizzled LDS offsets (all loop-invariant) ----
    int koff[8][2];
#pragma unroll
    for (int kvb = 0; kvb < 8; ++kvb) {
        const int kr = kvb * 16 + q15;
        koff[kvb][0] = (kr * 64 + g * 8) ^ ((kr & 7) << 3);
        koff[kvb][1] = (kr * 64 + 32 + g * 8) ^ ((kr & 7) << 3);
    }
    int voff[4][4];
#pragma unroll
    for (int db = 0; db < 4; ++db) {
        const int vr = db * 16 + q15;
#pragma unroll
        for (int ks = 0; ks < 4; ++ks)
            voff[db][ks] = (vr * KVB + ks * 32 + g * 8) ^ ((vr & 7) << 3);
    }
    int voffE[4];
#pragma unroll
    for (int ks = 0; ks < 4; ++ks) {
        const int rv = 64 + q15;
        voffE[ks] = (rv * KVB + ks * 32 + g * 8) ^ ((rv & 7) << 3);
    }
    // staging assignments + write offsets
    const int kr_s = t >> 1, sh = t & 1;          // K: row kr_s, 32-col half sh
    const int kq = t & 31, dg = t >> 5;           // V: kv-quad kq, d-chunk dg
    const int slot4 = (kq >> 3) * 32 + (kq & 3) * 8 + ((kq >> 2) & 1) * 4;
    int kwoff[4];
#pragma unroll
    for (int i = 0; i < 4; ++i)
        kwoff[i] = (kr_s * 64 + (sh * 4 + i) * 8) ^ ((kr_s & 7) << 3);
    int vwoff[8];
#pragma unroll
    for (int i = 0; i < 8; ++i) {
        const int d = dg * 8 + i;
        vwoff[i] = (d * KVB + slot4) ^ ((d & 7) << 3);
    }
    const unsigned short* Kg = qkv + (size_t)kr_s * D3 + DD + h * HIDC + sh * 32;
    const unsigned short* Vg = qkv + (size_t)(4 * kq) * D3 + 2 * DD + h * HIDC + dg * 8;

    short8 kreg[4], vreg[4];

    auto LOAD_KV = [&](int kb) {
        const size_t off = (size_t)kb * KVB * D3;
#pragma unroll
        for (int i = 0; i < 4; ++i) kreg[i] = *(const short8*)(Kg + off + i * 8);
#pragma unroll
        for (int jj = 0; jj < 4; ++jj) vreg[jj] = *(const short8*)(Vg + off + (size_t)jj * D3);
    };
    auto WRITE_KV = [&](unsigned short* KD, unsigned short* VD) {
#pragma unroll
        for (int i = 0; i < 4; ++i)
            *(short8*)&KD[kwoff[i]] = kreg[i];
        const unsigned int* w0 = (const unsigned int*)&vreg[0];
        const unsigned int* w1 = (const unsigned int*)&vreg[1];
        const unsigned int* w2 = (const unsigned int*)&vreg[2];
        const unsigned int* w3 = (const unsigned int*)&vreg[3];
#pragma unroll
        for (int i = 0; i < 8; ++i) {
            const unsigned int sel = (i & 1) ? 0x07060302u : 0x05040100u;
            uint2v pk;
            pk.x = __builtin_amdgcn_perm(w1[i >> 1], w0[i >> 1], sel);
            pk.y = __builtin_amdgcn_perm(w3[i >> 1], w2[i >> 1], sel);
            *(uint2v*)&VD[vwoff[i]] = pk;
        }
    };

    // QK^T swapped into dst: dst[kvb][r] = S^T[kv = kvb*16 + g*4 + r][q = q15]
    auto QK = [&](const unsigned short* BK, f32x4* dst) {
        __builtin_amdgcn_s_setprio(1);
#pragma unroll
        for (int kvb = 0; kvb < 8; ++kvb) {
            const short8 kf0 = *(const short8*)&BK[koff[kvb][0]];
            const short8 kf1 = *(const short8*)&BK[koff[kvb][1]];
            f32x4 acc = (f32x4){0.f, 0.f, 0.f, 0.f};
            acc = __builtin_amdgcn_mfma_f32_16x16x32_bf16(kf0, qf0, acc, 0, 0, 0);
            acc = __builtin_amdgcn_mfma_f32_16x16x32_bf16(kf1, qf1, acc, 0, 0, 0);
            dst[kvb] = acc;
        }
        __builtin_amdgcn_s_setprio(0);
    };

    // softmax(st) -> pf; PV from BV. Consumes st of the CURRENT tile.
    auto SMPV = [&](f32x4* st, const unsigned short* BV) {
        // row max via v_max3 tree (16 ops for 32 values)
        float pm0 = max3f(st[0][0], st[0][1], st[0][2]);
        float pm1 = max3f(st[0][3], st[1][0], st[1][1]);
        float pm2 = max3f(st[1][2], st[1][3], st[2][0]);
        float pm3 = max3f(st[2][1], st[2][2], st[2][3]);
        float pm4 = max3f(st[3][0], st[3][1], st[3][2]);
        float pm5 = max3f(st[3][3], st[4][0], st[4][1]);
        float pm6 = max3f(st[4][2], st[4][3], st[5][0]);
        float pm7 = max3f(st[5][1], st[5][2], st[5][3]);
        float pm8 = max3f(st[6][0], st[6][1], st[6][2]);
        float pm9 = max3f(st[6][3], st[7][0], st[7][1]);
        float pmA = max3f(st[7][2], st[7][3], pm0);
        float r0 = max3f(pm1, pm2, pm3);
        float r1 = max3f(pm4, pm5, pm6);
        float r2 = max3f(pm7, pm8, pm9);
        float pmax = max3f(r0, r1, r2);
        pmax = fmaxf(pmax, pmA);
        pmax = fmaxf(pmax, __shfl_xor(pmax, 16, 64));
        pmax = fmaxf(pmax, __shfl_xor(pmax, 32, 64));
        if (!__all(pmax <= m_run + 11.f)) {     // defer-max (T13), exp2 domain
            const float mnew = fmaxf(m_run, pmax);
            const float f = exp2f(m_run - mnew);
#pragma unroll
            for (int db = 0; db < 4; ++db) O[db] *= f;
            O5 *= f;                            // l rescales with O
            m_run = mnew;
        }

        // P in registers: pf[ks] = lane's own words (sigma alignment)
        short8 pf[4];
#pragma unroll
        for (int ks = 0; ks < 4; ++ks) {
            float e0 = exp2f(st[2*ks  ][0] - m_run), e1 = exp2f(st[2*ks  ][1] - m_run);
            float e2 = exp2f(st[2*ks  ][2] - m_run), e3 = exp2f(st[2*ks  ][3] - m_run);
            float e4 = exp2f(st[2*ks+1][0] - m_run), e5 = exp2f(st[2*ks+1][1] - m_run);
            float e6 = exp2f(st[2*ks+1][2] - m_run), e7 = exp2f(st[2*ks+1][3] - m_run);
            union { unsigned int u[4]; short8 s8; } pu;
            pu.u[0] = cvt_pk_bf16(e0, e1);
            pu.u[1] = cvt_pk_bf16(e2, e3);
            pu.u[2] = cvt_pk_bf16(e4, e5);
            pu.u[3] = cvt_pk_bf16(e6, e7);
            pf[ks] = pu.s8;
        }

        // PV swapped: O^T[d][q] += Vt(sigma) @ P^T ; ones-row block gives l
        __builtin_amdgcn_s_setprio(1);
#pragma unroll
        for (int db = 0; db < 4; ++db) {
#pragma unroll
            for (int ks = 0; ks < 4; ++ks) {
                const short8 vf = *(const short8*)&BV[voff[db][ks]];
                O[db] = __builtin_amdgcn_mfma_f32_16x16x32_bf16(vf, pf[ks], O[db], 0, 0, 0);
            }
        }
#pragma unroll
        for (int ks = 0; ks < 4; ++ks) {
            const short8 vfE = *(const short8*)&BV[voffE[ks]];
            O5 = __builtin_amdgcn_mfma_f32_16x16x32_bf16(vfE, pf[ks], O5, 0, 0, 0);
        }
        __builtin_amdgcn_s_setprio(0);
    };

    // pipelined tile step: stc = current tile's scores; stn gets next tile's.
    // CK/CV = current buffers (kb); NK/NV = next buffers (kb+1, resident).
    auto STEP = [&](int kb, unsigned short* CK, unsigned short* CV,
                    const unsigned short* NK, const unsigned short* NV,
                    f32x4* stc, f32x4* stn) {
        (void)NV;
        const int kbn = kb + 1, kbw = kb + 2;
        if (kbw < NTT) LOAD_KV(kbw);           // T14: issue kb+2 loads early
        if (kbn < NTT) QK(NK, stn);            // T15: next tile's QK before SM
        SMPV(stc, CV);                          // softmax(kb) + PV(kb)
        if (kbw < NTT) {
            __syncthreads();                    // all waves done reading CK/CV
            WRITE_KV(CK, CV);                   // kb+2 into current buffers
            __syncthreads();                    // visible for next STEP's QK
        }
    };

    // prologue: ones-block rows (64..79) of both Vt buffers; tiles 0,1 to LDS;
    // tile-0 scores precomputed (overlaps tile-1 load latency).
    {
        const int d = 64 + (t >> 4), c = (t & 15) * 8;
        short8 iv;
#pragma unroll
        for (int i = 0; i < 8; ++i)
            iv[i] = (short)((d == 64) ? 0x3F80 : 0);   // bf16 1.0 on row 64
        const int ofs = (d * KVB + c) ^ ((d & 7) << 3);
        *(short8*)&Vt0[ofs] = iv;
        *(short8*)&Vt1[ofs] = iv;
    }
    f32x4 st_a[8], st_b[8];
    LOAD_KV(0);
    WRITE_KV(Ks0, Vt0);
    __syncthreads();
    LOAD_KV(1);
    QK(Ks0, st_a);                 // tile 0 scores (hides LOAD(1) latency)
    WRITE_KV(Ks1, Vt1);
    __syncthreads();

    for (int kb = 0; kb < NTT; kb += 2) {
        STEP(kb,     Ks0, Vt0, Ks1, Vt1, st_a, st_b);
        STEP(kb + 1, Ks1, Vt1, Ks0, Vt0, st_b, st_a);
    }

    // l lives in O5[0] on lanes 0..15 (d-row 0 of ones-block), col = q
    const float lsum = __shfl(O5[0], q15, 64);
    const float linv = 1.f / lsum;
#pragma unroll
    for (int db = 0; db < 4; ++db) {
        uint2v pk;
        pk.x = (unsigned int)f2bf(O[db][0] * linv) | ((unsigned int)f2bf(O[db][1] * linv) << 16);
        pk.y = (unsigned int)f2bf(O[db][2] * linv) | ((unsigned int)f2bf(O[db][3] * linv) << 16);
        *(uint2v*)&aob[(size_t)(qbase + q15) * DD + h * HIDC + db * 16 + g * 4] = pk;
    }
}

// ---------------------------------------------------------------------------
// Fused residual + LayerNorm: out = LN(hin + dlt)*g + b. dlt is bf16
// (out-proj/ff2 emit bf16) -> packed uint loads; thread handles elems 2t,2t+1.
// ---------------------------------------------------------------------------
__global__ __launch_bounds__(256) void ln_fused(const float* __restrict__ hin,
                                                const unsigned short* __restrict__ dlt,
                                                const float* __restrict__ g,
                                                const float* __restrict__ b,
                                                float* __restrict__ out,
                                                unsigned short* __restrict__ outb)
{
    __shared__ float red[256];
    const int r = blockIdx.x, t = threadIdx.x;
    const size_t base = (size_t)r * DD;
    float2 hv = *(const float2*)(hin + base + 2 * t);
    unsigned int dv = *(const unsigned int*)(dlt + base + 2 * t);
    float v0 = hv.x + bf2f((unsigned short)(dv & 0xffffu));
    float v1 = hv.y + bf2f((unsigned short)(dv >> 16));
    red[t] = v0 + v1;
    __syncthreads();
    for (int off = 128; off > 0; off >>= 1) { if (t < off) red[t] += red[t + off]; __syncthreads(); }
    float mu = red[0] * (1.f / 512.f);
    __syncthreads();
    float d0 = v0 - mu, d1 = v1 - mu;
    red[t] = d0 * d0 + d1 * d1;
    __syncthreads();
    for (int off = 128; off > 0; off >>= 1) { if (t < off) red[t] += red[t + off]; __syncthreads(); }
    float rs = rsqrtf(red[0] * (1.f / 512.f) + 1e-5f);
    float2 gv = *(const float2*)(g + 2 * t);
    float2 bv = *(const float2*)(b + 2 * t);
    float o0 = d0 * rs * gv.x + bv.x;
    float o1 = d1 * rs * gv.y + bv.y;
    float2 ov; ov.x = o0; ov.y = o1;
    *(float2*)(out + base + 2 * t) = ov;
    if (outb) {
        unsigned int pk = (unsigned int)f2bf(o0) | ((unsigned int)f2bf(o1) << 16);
        *(unsigned int*)(outb + base + 2 * t) = pk;
    }
}

// ---------------------------------------------------------------------------
extern "C" void kernel_launch(void* const* d_in, const int* in_sizes, int n_in,
                              void* d_out, int out_size, void* d_ws, size_t ws_size,
                              hipStream_t stream)
{
    (void)in_sizes; (void)n_in; (void)out_size; (void)ws_size;

    const float* x        = (const float*)d_in[0];
    const int*   ei       = (const int*)  d_in[1];
    const float* lin_w    = (const float*)d_in[3];
    const float* att_src  = (const float*)d_in[4];
    const float* att_dst  = (const float*)d_in[5];
    const float* gat_bias = (const float*)d_in[6];
    const float* qkv_w    = (const float*)d_in[7];
    const float* qkv_b    = (const float*)d_in[8];
    const float* out_w    = (const float*)d_in[9];
    const float* out_b    = (const float*)d_in[10];
    const float* ln1_g    = (const float*)d_in[11];
    const float* ln1_b    = (const float*)d_in[12];
    const float* ff1_w    = (const float*)d_in[13];
    const float* ff1_b    = (const float*)d_in[14];
    const float* ff2_w    = (const float*)d_in[15];
    const float* ff2_b    = (const float*)d_in[16];
    const float* ln2_g    = (const float*)d_in[17];
    const float* ln2_b    = (const float*)d_in[18];

    char* wsb = (char*)d_ws;
    size_t o = 0;
    auto alloc = [&](size_t bytes) { char* p = wsb + o; o += (bytes + 255) & ~(size_t)255; return p; };

    unsigned short* hlin_bf = (unsigned short*)alloc((size_t)NN * DD * 2);
    unsigned short* hbf     = (unsigned short*)alloc((size_t)NN * DD * 2);
    unsigned short* qkv16   = (unsigned short*)alloc((size_t)NN * D3 * 2);
    unsigned short* aob     = (unsigned short*)alloc((size_t)NN * DD * 2);
    unsigned short* ff1obf  = (unsigned short*)alloc((size_t)NN * DFF2 * 2);
    unsigned short* dltbf   = (unsigned short*)alloc((size_t)NN * DD * 2);
    float* hcur  = (float*)alloc((size_t)NN * DD * 4);
    float* a_src = (float*)alloc((size_t)NN * HH * 4);
    float* a_dst = (float*)alloc((size_t)NN * HH * 4);
    int* counts     = (int*)alloc(NN * 4);
    int* cursor     = (int*)alloc(NN * 4);
    int* offsets    = (int*)alloc((NN + 1) * 4);
    int* src_sorted = (int*)alloc(ENE * 4);
    unsigned short* xbf    = (unsigned short*)alloc((size_t)NN * IND * 2);
    unsigned short* linwbf = (unsigned short*)alloc((size_t)DD * IND * 2);
    unsigned short* qkvwbf = (unsigned short*)alloc((size_t)2 * D3 * DD * 2);
    unsigned short* outwbf = (unsigned short*)alloc((size_t)2 * DD * DD * 2);
    unsigned short* ff1wbf = (unsigned short*)alloc((size_t)2 * DFF2 * DD * 2);
    unsigned short* ff2wbf = (unsigned short*)alloc((size_t)2 * DD * DFF2 * 2);

    // --- weight/x conversion to bf16 (one pass) ---
    CvtJobs jb;
    jb.src[0] = x;      jb.dst[0] = xbf;    jb.n[0] = NN * IND;
    jb.src[1] = lin_w;  jb.dst[1] = linwbf; jb.n[1] = DD * IND;
    jb.src[2] = qkv_w;  jb.dst[2] = qkvwbf; jb.n[2] = 2 * D3 * DD;
    jb.src[3] = out_w;  jb.dst[3] = outwbf; jb.n[3] = 2 * DD * DD;
    jb.src[4] = ff1_w;  jb.dst[4] = ff1wbf; jb.n[4] = 2 * DFF2 * DD;
    jb.src[5] = ff2_w;  jb.dst[5] = ff2wbf; jb.n[5] = 2 * DD * DFF2;
    int cvt_total = jb.n[0]+jb.n[1]+jb.n[2]+jb.n[3]+jb.n[4]+jb.n[5];
    cvt_many<<<(cvt_total/4 + 255)/256, 256, 0, stream>>>(jb, cvt_total);

    // --- GAT ---
    hipMemsetAsync(counts, 0, 2 * NN * sizeof(int), stream);  // counts + cursor (adjacent)
    gemm64<<<dim3(DD/64, NN/64), 256, 0, stream>>>(xbf, linwbf, nullptr, hlin_bf,
                                                   NN, IND, DD, 1);
    att_proj<<<(NN*HH + 255)/256, 256, 0, stream>>>(hlin_bf, att_src, att_dst, a_src, a_dst);
    hist_kernel<<<(ENE + 255)/256, 256, 0, stream>>>(ei, counts);
    scan_kernel<<<1, 1024, 0, stream>>>(counts, offsets);
    scatter_kernel<<<(ENE + 255)/256, 256, 0, stream>>>(ei, offsets, cursor, src_sorted);
    gat_node<<<NN, 256, 0, stream>>>(hlin_bf, a_src, a_dst, offsets, src_sorted, gat_bias,
                                     hcur, hbf);

    // --- 2 transformer encoder layers (post-norm) ---
    for (int i = 0; i < 2; ++i) {
        gemm64<<<dim3(D3/64, NN/64), 256, 0, stream>>>(hbf, qkvwbf + (size_t)i*D3*DD,
                                                       qkv_b + (size_t)i*D3, qkv16,
                                                       NN, DD, D3, 1 | 4);
        attn_mfma<<<dim3(NN/64 * HH), 256, 0, stream>>>(qkv16, aob);
        gemm64<<<dim3(DD/64, NN/64), 256, 0, stream>>>(aob, outwbf + (size_t)i*DD*DD,
                                                       out_b + (size_t)i*DD, dltbf,
                                                       NN, DD, DD, 1);
        ln_fused<<<NN, 256, 0, stream>>>(hcur, dltbf, ln1_g + (size_t)i*DD, ln1_b + (size_t)i*DD,
                                         hcur, hbf);
        gemm64<<<dim3(DFF2/64, NN/64), 256, 0, stream>>>(hbf, ff1wbf + (size_t)i*DFF2*DD,
                                                         ff1_b + (size_t)i*DFF2, ff1obf,
                                                         NN, DD, DFF2, 1 | 2);
        gemm64<<<dim3(DD/64, NN/64), 256, 0, stream>>>(ff1obf, ff2wbf + (size_t)i*DD*DFF2,
                                                       ff2_b + (size_t)i*DD, dltbf,
                                                       NN, DFF2, DD, 1);
        float* outp = (i == 1) ? (float*)d_out : hcur;
        unsigned short* outbp = (i == 1) ? nullptr : hbf;
        ln_fused<<<NN, 256, 0, stream>>>(hcur, dltbf, ln2_g + (size_t)i*DD, ln2_b + (size_t)i*DD,
                                         outp, outbp);
    }
}

// Round 13
// 328.860 us; speedup vs baseline: 1.3211x; 1.3211x over previous
//
#include <hip/hip_runtime.h>
#include <math.h>

// Problem constants (match reference)
#define NN    4096
#define EE    131072
#define ENE   (EE + NN)      // edges + self loops = 135168
#define IND   128
#define HH    8
#define HIDC  64
#define DD    512
#define D3    1536
#define DFF2  256

typedef __attribute__((ext_vector_type(8))) short short8;
typedef __attribute__((ext_vector_type(4))) float f32x4;
typedef __attribute__((ext_vector_type(2))) unsigned int uint2v;

__device__ __forceinline__ float lrelu02(float x) { return x >= 0.f ? x : 0.2f * x; }

// round-to-nearest-even f32 -> bf16 bits (inputs finite)
__device__ __forceinline__ unsigned short f2bf(float x) {
    unsigned int u = __float_as_uint(x);
    u += 0x7fffu + ((u >> 16) & 1u);
    return (unsigned short)(u >> 16);
}
__device__ __forceinline__ float bf2f(unsigned short u) {
    return __uint_as_float((unsigned int)u << 16);
}
// packed RNE f32x2 -> bf16x2 (T12 recipe)
__device__ __forceinline__ unsigned int cvt_pk_bf16(float lo, float hi) {
    unsigned int r;
    asm("v_cvt_pk_bf16_f32 %0, %1, %2" : "=v"(r) : "v"(lo), "v"(hi));
    return r;
}
// 3-input max (T17)
__device__ __forceinline__ float max3f(float a, float b, float c) {
    float r;
    asm("v_max3_f32 %0, %1, %2, %3" : "=v"(r) : "v"(a), "v"(b), "v"(c));
    return r;
}

// ---------------------------------------------------------------------------
// Batched fp32 -> bf16 conversion (weights + x), one launch, 6 segments.
// ---------------------------------------------------------------------------
struct CvtJobs {
    const float* src[6];
    unsigned short* dst[6];
    int n[6];
};

__global__ __launch_bounds__(256) void cvt_many(CvtJobs jb, int total)
{
    int i = (blockIdx.x * 256 + threadIdx.x) * 4;
    if (i >= total) return;
    int s = 0;
    while (i >= jb.n[s]) { i -= jb.n[s]; ++s; }
    float4 v = *(const float4*)(jb.src[s] + i);
    unsigned int lo = (unsigned int)f2bf(v.x) | ((unsigned int)f2bf(v.y) << 16);
    unsigned int hi = (unsigned int)f2bf(v.z) | ((unsigned int)f2bf(v.w) << 16);
    uint2v pk; pk.x = lo; pk.y = hi;
    *(uint2v*)(jb.dst[s] + i) = pk;
}

// ---------------------------------------------------------------------------
// bf16 MFMA GEMM, 64x64 tile (grid-utilization per G11; handles all GEMMs).
// flags: bit0 = bf16 out, bit1 = relu, bit2 = scale cols<512 by 0.125*log2e.
// ---------------------------------------------------------------------------
__global__ __launch_bounds__(256) void gemm64(const unsigned short* __restrict__ A,
                                              const unsigned short* __restrict__ W,
                                              const float* __restrict__ bias,
                                              void* __restrict__ C,
                                              int M, int K, int N, int flags)
{
    __shared__ __align__(16) unsigned short As[64 * 64];
    __shared__ __align__(16) unsigned short Bs[64 * 64];

    const int t = threadIdx.x, lane = t & 63, w = t >> 6;
    const int wr = w >> 1, wc = w & 1;
    const int bm = blockIdx.y * 64, bn = blockIdx.x * 64;
    const int q = lane & 15, g = lane >> 4;

    f32x4 acc[2][2];
#pragma unroll
    for (int m = 0; m < 2; ++m)
#pragma unroll
        for (int n = 0; n < 2; ++n) acc[m][n] = (f32x4){0.f, 0.f, 0.f, 0.f};

    const int srow = t >> 2, sh = t & 3;
    const unsigned short* Ag = A + (size_t)(bm + srow) * K + sh * 16;
    const unsigned short* Wg = W + (size_t)(bn + srow) * K + sh * 16;
    int wofs[2];
#pragma unroll
    for (int i = 0; i < 2; ++i)
        wofs[i] = srow * 128 + ((((sh * 2 + i) * 16) ^ ((srow & 7) << 4)));

    for (int k0 = 0; k0 < K; k0 += 64) {
        short8 av[2], bv[2];
#pragma unroll
        for (int i = 0; i < 2; ++i) {
            av[i] = *(const short8*)(Ag + k0 + i * 8);
            bv[i] = *(const short8*)(Wg + k0 + i * 8);
        }
        __syncthreads();
#pragma unroll
        for (int i = 0; i < 2; ++i) {
            *(short8*)((char*)As + wofs[i]) = av[i];
            *(short8*)((char*)Bs + wofs[i]) = bv[i];
        }
        __syncthreads();

        short8 af[2][2], bfr[2][2];
#pragma unroll
        for (int m = 0; m < 2; ++m) {
            const int row = wr * 32 + m * 16 + q;
#pragma unroll
            for (int kk = 0; kk < 2; ++kk)
                af[kk][m] = *(const short8*)((const char*)As +
                    row * 128 + ((((kk * 4 + g) * 16) ^ ((row & 7) << 4))));
        }
#pragma unroll
        for (int n = 0; n < 2; ++n) {
            const int row = wc * 32 + n * 16 + q;
#pragma unroll
            for (int kk = 0; kk < 2; ++kk)
                bfr[kk][n] = *(const short8*)((const char*)Bs +
                    row * 128 + ((((kk * 4 + g) * 16) ^ ((row & 7) << 4))));
        }
#pragma unroll
        for (int kk = 0; kk < 2; ++kk)
#pragma unroll
            for (int m = 0; m < 2; ++m)
#pragma unroll
                for (int n = 0; n < 2; ++n)
                    acc[m][n] = __builtin_amdgcn_mfma_f32_16x16x32_bf16(
                        bfr[kk][n], af[kk][m], acc[m][n], 0, 0, 0);
    }

    const int obf = flags & 1, orelu = flags & 2, oqs = flags & 4;
#pragma unroll
    for (int m = 0; m < 2; ++m) {
        const int row = bm + wr * 32 + m * 16 + q;
#pragma unroll
        for (int n = 0; n < 2; ++n) {
            const int col0 = bn + wc * 32 + n * 16 + g * 4;
            f32x4 v = acc[m][n];
            if (bias) {
                float4 bv4 = *(const float4*)(bias + col0);
                v[0] += bv4.x; v[1] += bv4.y; v[2] += bv4.z; v[3] += bv4.w;
            }
            if (oqs && col0 < DD) {
                // 1/sqrt(64) * log2(e): attention runs softmax in exp2 domain
                const float qs = 0.18033688f;
                v[0] *= qs; v[1] *= qs; v[2] *= qs; v[3] *= qs;
            }
            if (orelu) {
                v[0] = fmaxf(v[0], 0.f); v[1] = fmaxf(v[1], 0.f);
                v[2] = fmaxf(v[2], 0.f); v[3] = fmaxf(v[3], 0.f);
            }
            if (obf) {
                uint2v pk;
                pk.x = (unsigned int)f2bf(v[0]) | ((unsigned int)f2bf(v[1]) << 16);
                pk.y = (unsigned int)f2bf(v[2]) | ((unsigned int)f2bf(v[3]) << 16);
                *(uint2v*)((unsigned short*)C + (size_t)row * N + col0) = pk;
            } else {
                float4 o; o.x = v[0]; o.y = v[1]; o.z = v[2]; o.w = v[3];
                *(float4*)((float*)C + (size_t)row * N + col0) = o;
            }
        }
    }
}

// ---------------------------------------------------------------------------
// a_src[n,h] = <hlin[n,h,:], att_src[h,:]>, same for dst. hlin is bf16.
// ---------------------------------------------------------------------------
__global__ void att_proj(const unsigned short* __restrict__ hlin,
                         const float* __restrict__ att_s,
                         const float* __restrict__ att_d,
                         float* __restrict__ a_src, float* __restrict__ a_dst)
{
    int idx = blockIdx.x * 256 + threadIdx.x;
    if (idx >= NN * HH) return;
    int n = idx >> 3, h = idx & 7;
    const unsigned short* hp = hlin + (size_t)n * DD + h * HIDC;
    const float* as = att_s + h * HIDC;
    const float* ad = att_d + h * HIDC;
    float s1 = 0.f, s2 = 0.f;
#pragma unroll 8
    for (int c = 0; c < HIDC; ++c) {
        float hv = bf2f(hp[c]);
        s1 += hv * as[c]; s2 += hv * ad[c];
    }
    a_src[idx] = s1;
    a_dst[idx] = s2;
}

// ---------------------------------------------------------------------------
// CSR build: histogram over dst (incl. self-loops), scan, scatter src indices.
// ---------------------------------------------------------------------------
__global__ void hist_kernel(const int* __restrict__ ei, int* __restrict__ counts)
{
    int i = blockIdx.x * 256 + threadIdx.x;
    if (i >= ENE) return;
    int dst = (i < EE) ? ei[EE + i] : (i - EE);
    atomicAdd(&counts[dst], 1);
}

__global__ __launch_bounds__(1024) void scan_kernel(const int* __restrict__ counts,
                                                    int* __restrict__ offsets)
{
    __shared__ int sums[1024];
    int t = threadIdx.x;
    int v0 = counts[t*4+0], v1 = counts[t*4+1], v2 = counts[t*4+2], v3 = counts[t*4+3];
    sums[t] = v0 + v1 + v2 + v3;
    __syncthreads();
    for (int off = 1; off < 1024; off <<= 1) {
        int x = (t >= off) ? sums[t - off] : 0;
        __syncthreads();
        sums[t] += x;
        __syncthreads();
    }
    int pre = (t > 0) ? sums[t-1] : 0;
    offsets[t*4+0] = pre;
    offsets[t*4+1] = pre + v0;
    offsets[t*4+2] = pre + v0 + v1;
    offsets[t*4+3] = pre + v0 + v1 + v2;
    if (t == 1023) offsets[4096] = sums[1023];
}

__global__ void scatter_kernel(const int* __restrict__ ei, const int* __restrict__ offs,
                               int* __restrict__ cursor, int* __restrict__ src_sorted)
{
    int i = blockIdx.x * 256 + threadIdx.x;
    if (i >= ENE) return;
    int s, d;
    if (i < EE) { s = ei[i]; d = ei[EE + i]; } else { s = d = i - EE; }
    int pos = atomicAdd(&cursor[d], 1);
    src_sorted[offs[d] + pos] = s;
}

// ---------------------------------------------------------------------------
// GAT aggregation: one block per dst node. hlin is bf16. Pass-2 gather now
// loads packed uint (2 bf16, 4B/lane) per edge-row: thread t owns columns
// 2t, 2t+1 (same head: (2t)>>6 == t>>5) — replaces two 2B scalar streams.
// ---------------------------------------------------------------------------
__global__ __launch_bounds__(256) void gat_node(const unsigned short* __restrict__ hlin,
                                                const float* __restrict__ a_src,
                                                const float* __restrict__ a_dst,
                                                const int* __restrict__ offs,
                                                const int* __restrict__ src_sorted,
                                                const float* __restrict__ bias,
                                                float* __restrict__ out,
                                                unsigned short* __restrict__ outb)
{
    __shared__ float adst[8];
    __shared__ float emax[8];
    __shared__ float denom[8];
    __shared__ float red[256];
    __shared__ float p_lds[16][8];
    __shared__ int   srcs[16];

    const int n = blockIdx.x, t = threadIdx.x;
    if (t < 8) { adst[t] = a_dst[n * 8 + t]; denom[t] = 0.f; }
    const int off0 = offs[n];
    const int deg  = offs[n+1] - off0;
    __syncthreads();

    const int h = t & 7, slot = t >> 3;
    float mx = -3.0e38f;
    for (int j = slot; j < deg; j += 32) {
        int s = src_sorted[off0 + j];
        mx = fmaxf(mx, a_src[s * 8 + h] + adst[h]);
    }
    red[t] = mx;
    __syncthreads();
    for (int half = 128; half >= 8; half >>= 1) {
        if (t < half) red[t] = fmaxf(red[t], red[t + half]);
        __syncthreads();
    }
    if (t < 8) emax[t] = lrelu02(red[t]);
    __syncthreads();

    float acc0 = 0.f, acc1 = 0.f;
    const int c0 = 2 * t;            // columns 2t, 2t+1
    const int hh = t >> 5;           // head of both columns
    for (int base = 0; base < deg; base += 16) {
        int cnt = min(16, deg - base);
        if (t < cnt * 8) {
            int j = base + (t >> 3);
            int s = src_sorted[off0 + j];
            if ((t & 7) == 0) srcs[t >> 3] = s;
            float x = a_src[s * 8 + (t & 7)] + adst[t & 7];
            float p = __expf(lrelu02(x) - emax[t & 7]);
            p_lds[t >> 3][t & 7] = p;
            atomicAdd(&denom[t & 7], p);
        }
        __syncthreads();
        for (int jj = 0; jj < cnt; ++jj) {
            int s = srcs[jj];
            unsigned int hv = *(const unsigned int*)(hlin + (size_t)s * DD + c0);
            float p = p_lds[jj][hh];
            acc0 += p * bf2f((unsigned short)(hv & 0xffffu));
            acc1 += p * bf2f((unsigned short)(hv >> 16));
        }
        __syncthreads();
    }
    const float dinv = 1.f / (denom[hh] + 1e-16f);
    float o0 = acc0 * dinv + bias[c0];
    float o1 = acc1 * dinv + bias[c0 + 1];
    float2 ov; ov.x = o0; ov.y = o1;
    *(float2*)(out + (size_t)n * DD + c0) = ov;
    unsigned int pk = (unsigned int)f2bf(o0) | ((unsigned int)f2bf(o1) << 16);
    *(unsigned int*)(outb + (size_t)n * DD + c0) = pk;
}

// ---------------------------------------------------------------------------
// bf16 MFMA flash attention — r11 passing version (82us). r10 (fewer waves)
// and r12 (cross-tile pipeline) both REGRESSED: any ILP scheme that costs
// TLP loses here. 256 thr = 4 waves, wave = 16 q rows; dbuf, 1 barrier/tile,
// hoisted offsets, zero-LDS P (sigma Vt), exp2 softmax, defer-max, ones-row
// l via MFMA, head-per-XCD.
// ---------------------------------------------------------------------------
#define KVB 128
#define NTT (NN / KVB)   // 32 tiles

__global__ __launch_bounds__(256) void attn_mfma(const unsigned short* __restrict__ qkv,
                                                 unsigned short* __restrict__ aob)
{
    __shared__ __align__(16) unsigned short Ks0[KVB * 64];
    __shared__ __align__(16) unsigned short Vt0[80 * KVB];   // rows 64..79: ones-block
    __shared__ __align__(16) unsigned short Ks1[KVB * 64];
    __shared__ __align__(16) unsigned short Vt1[80 * KVB];

    const int t = threadIdx.x;
    const int w = t >> 6, lane = t & 63;
    const int q15 = lane & 15, g = lane >> 4;

    // head-per-XCD: h = bid&7 pins each head's K/V (1MB) + Q to one XCD's L2.
    const int fid = blockIdx.x;
    const int h = fid & 7, qb = fid >> 3;
    const int qbase = qb * 64 + w * 16;

    // Q fragments (0.125*log2e pre-folded by QKV GEMM epilogue)
    const unsigned short* qrow = qkv + (size_t)(qbase + q15) * D3 + h * HIDC;
    const short8 qf0 = *(const short8*)(qrow + g * 8);
    const short8 qf1 = *(const short8*)(qrow + 32 + g * 8);

    f32x4 O[4];
#pragma unroll
    for (int db = 0; db < 4; ++db) O[db] = (f32x4){0.f, 0.f, 0.f, 0.f};
    f32x4 O5 = (f32x4){0.f, 0.f, 0.f, 0.f};     // ones-row block: O5[0] = l (lanes 0..15)
    float m_run = -3.0e38f;

    // ---- hoisted swizzled LDS offsets (all loop-invariant) ----
    int koff[8][2];
#pragma unroll
    for (int kvb = 0; kvb < 8; ++kvb) {
        const int kr = kvb * 16 + q15;
        koff[kvb][0] = (kr * 64 + g * 8) ^ ((kr & 7) << 3);
        koff[kvb][1] = (kr * 64 + 32 + g * 8) ^ ((kr & 7) << 3);
    }
    int voff[4][4];
#pragma unroll
    for (int db = 0; db < 4; ++db) {
        const int vr = db * 16 + q15;
#pragma unroll
        for (int ks = 0; ks < 4; ++ks)
            voff[db][ks] = (vr * KVB + ks * 32 + g * 8) ^ ((vr & 7) << 3);
    }
    int voffE[4];
#pragma unroll
    for (int ks = 0; ks < 4; ++ks) {
        const int rv = 64 + q15;
        voffE[ks] = (rv * KVB + ks * 32 + g * 8) ^ ((rv & 7) << 3);
    }
    // staging assignments + write offsets
    const int kr_s = t >> 1, sh = t & 1;          // K: row kr_s, 32-col half sh
    const int kq = t & 31, dg = t >> 5;           // V: kv-quad kq, d-chunk dg
    const int slot4 = (kq >> 3) * 32 + (kq & 3) * 8 + ((kq >> 2) & 1) * 4;
    int kwoff[4];
#pragma unroll
    for (int i = 0; i < 4; ++i)
        kwoff[i] = (kr_s * 64 + (sh * 4 + i) * 8) ^ ((kr_s & 7) << 3);
    int vwoff[8];
#pragma unroll
    for (int i = 0; i < 8; ++i) {
        const int d = dg * 8 + i;
        vwoff[i] = (d * KVB + slot4) ^ ((d & 7) << 3);
    }
    const unsigned short* Kg = qkv + (size_t)kr_s * D3 + DD + h * HIDC + sh * 32;
    const unsigned short* Vg = qkv + (size_t)(4 * kq) * D3 + 2 * DD + h * HIDC + dg * 8;

    short8 kreg[4], vreg[4];

    auto LOAD_KV = [&](int kb) {
        const size_t off = (size_t)kb * KVB * D3;
#pragma unroll
        for (int i = 0; i < 4; ++i) kreg[i] = *(const short8*)(Kg + off + i * 8);
#pragma unroll
        for (int jj = 0; jj < 4; ++jj) vreg[jj] = *(const short8*)(Vg + off + (size_t)jj * D3);
    };
    auto WRITE_KV = [&](unsigned short* KD, unsigned short* VD) {
#pragma unroll
        for (int i = 0; i < 4; ++i)
            *(short8*)&KD[kwoff[i]] = kreg[i];
        const unsigned int* w0 = (const unsigned int*)&vreg[0];
        const unsigned int* w1 = (const unsigned int*)&vreg[1];
        const unsigned int* w2 = (const unsigned int*)&vreg[2];
        const unsigned int* w3 = (const unsigned int*)&vreg[3];
#pragma unroll
        for (int i = 0; i < 8; ++i) {
            const unsigned int sel = (i & 1) ? 0x07060302u : 0x05040100u;
            uint2v pk;
            pk.x = __builtin_amdgcn_perm(w1[i >> 1], w0[i >> 1], sel);
            pk.y = __builtin_amdgcn_perm(w3[i >> 1], w2[i >> 1], sel);
            *(uint2v*)&VD[vwoff[i]] = pk;
        }
    };

    // one full tile body; BK/BV = compute buffers, NK/NV = next-tile buffers
    auto TILE = [&](int kb, const unsigned short* BK, const unsigned short* BV,
                    unsigned short* NK, unsigned short* NV) {
        const int kbn = kb + 1;
        if (kbn < NTT) LOAD_KV(kbn);           // T14: issue early

        // QK^T swapped: st[kvb][r] = S^T[kv = kvb*16 + g*4 + r][q = q15]
        f32x4 st[8];
        __builtin_amdgcn_s_setprio(1);
#pragma unroll
        for (int kvb = 0; kvb < 8; ++kvb) {
            const short8 kf0 = *(const short8*)&BK[koff[kvb][0]];
            const short8 kf1 = *(const short8*)&BK[koff[kvb][1]];
            f32x4 acc = (f32x4){0.f, 0.f, 0.f, 0.f};
            acc = __builtin_amdgcn_mfma_f32_16x16x32_bf16(kf0, qf0, acc, 0, 0, 0);
            acc = __builtin_amdgcn_mfma_f32_16x16x32_bf16(kf1, qf1, acc, 0, 0, 0);
            st[kvb] = acc;
        }
        __builtin_amdgcn_s_setprio(0);

        // row max via v_max3 tree (16 ops for 32 values)
        float pm0 = max3f(st[0][0], st[0][1], st[0][2]);
        float pm1 = max3f(st[0][3], st[1][0], st[1][1]);
        float pm2 = max3f(st[1][2], st[1][3], st[2][0]);
        float pm3 = max3f(st[2][1], st[2][2], st[2][3]);
        float pm4 = max3f(st[3][0], st[3][1], st[3][2]);
        float pm5 = max3f(st[3][3], st[4][0], st[4][1]);
        float pm6 = max3f(st[4][2], st[4][3], st[5][0]);
        float pm7 = max3f(st[5][1], st[5][2], st[5][3]);
        float pm8 = max3f(st[6][0], st[6][1], st[6][2]);
        float pm9 = max3f(st[6][3], st[7][0], st[7][1]);
        float pmA = max3f(st[7][2], st[7][3], pm0);
        float q0 = max3f(pm1, pm2, pm3);
        float q1 = max3f(pm4, pm5, pm6);
        float q2 = max3f(pm7, pm8, pm9);
        float pmax = max3f(q0, q1, q2);
        pmax = fmaxf(pmax, pmA);
        pmax = fmaxf(pmax, __shfl_xor(pmax, 16, 64));
        pmax = fmaxf(pmax, __shfl_xor(pmax, 32, 64));
        if (!__all(pmax <= m_run + 11.f)) {     // defer-max (T13), exp2 domain
            const float mnew = fmaxf(m_run, pmax);
            const float f = exp2f(m_run - mnew);
#pragma unroll
            for (int db = 0; db < 4; ++db) O[db] *= f;
            O5 *= f;                            // l rescales with O
            m_run = mnew;
        }

        // P in registers: pf[ks] = lane's own words (sigma alignment)
        short8 pf[4];
#pragma unroll
        for (int ks = 0; ks < 4; ++ks) {
            float e0 = exp2f(st[2*ks  ][0] - m_run), e1 = exp2f(st[2*ks  ][1] - m_run);
            float e2 = exp2f(st[2*ks  ][2] - m_run), e3 = exp2f(st[2*ks  ][3] - m_run);
            float e4 = exp2f(st[2*ks+1][0] - m_run), e5 = exp2f(st[2*ks+1][1] - m_run);
            float e6 = exp2f(st[2*ks+1][2] - m_run), e7 = exp2f(st[2*ks+1][3] - m_run);
            union { unsigned int u[4]; short8 s8; } pu;
            pu.u[0] = cvt_pk_bf16(e0, e1);
            pu.u[1] = cvt_pk_bf16(e2, e3);
            pu.u[2] = cvt_pk_bf16(e4, e5);
            pu.u[3] = cvt_pk_bf16(e6, e7);
            pf[ks] = pu.s8;
        }

        // PV swapped: O^T[d][q] += Vt(sigma) @ P^T ; ones-row block gives l
        __builtin_amdgcn_s_setprio(1);
#pragma unroll
        for (int db = 0; db < 4; ++db) {
#pragma unroll
            for (int ks = 0; ks < 4; ++ks) {
                const short8 vf = *(const short8*)&BV[voff[db][ks]];
                O[db] = __builtin_amdgcn_mfma_f32_16x16x32_bf16(vf, pf[ks], O[db], 0, 0, 0);
            }
        }
#pragma unroll
        for (int ks = 0; ks < 4; ++ks) {
            const short8 vfE = *(const short8*)&BV[voffE[ks]];
            O5 = __builtin_amdgcn_mfma_f32_16x16x32_bf16(vfE, pf[ks], O5, 0, 0, 0);
        }
        __builtin_amdgcn_s_setprio(0);

        // double-buffer handoff: ONE barrier per tile.
        if (kbn < NTT) {
            WRITE_KV(NK, NV);
            __syncthreads();
        }
    };

    // prologue: ones-block rows (64..79) of both Vt buffers, then tile 0.
    // short8 (16B) per thread -> 256 x 16B = 4KB = full coverage.
    {
        const int d = 64 + (t >> 4), c = (t & 15) * 8;
        short8 iv;
#pragma unroll
        for (int i = 0; i < 8; ++i)
            iv[i] = (short)((d == 64) ? 0x3F80 : 0);   // bf16 1.0 on row 64
        const int ofs = (d * KVB + c) ^ ((d & 7) << 3);
        *(short8*)&Vt0[ofs] = iv;
        *(short8*)&Vt1[ofs] = iv;
    }
    LOAD_KV(0);
    WRITE_KV(Ks0, Vt0);
    __syncthreads();

    for (int kb = 0; kb < NTT; kb += 2) {
        TILE(kb,     Ks0, Vt0, Ks1, Vt1);
        TILE(kb + 1, Ks1, Vt1, Ks0, Vt0);
    }

    // l lives in O5[0] on lanes 0..15 (d-row 0 of ones-block), col = q
    const float lsum = __shfl(O5[0], q15, 64);
    const float linv = 1.f / lsum;
#pragma unroll
    for (int db = 0; db < 4; ++db) {
        uint2v pk;
        pk.x = (unsigned int)f2bf(O[db][0] * linv) | ((unsigned int)f2bf(O[db][1] * linv) << 16);
        pk.y = (unsigned int)f2bf(O[db][2] * linv) | ((unsigned int)f2bf(O[db][3] * linv) << 16);
        *(uint2v*)&aob[(size_t)(qbase + q15) * DD + h * HIDC + db * 16 + g * 4] = pk;
    }
}

// ---------------------------------------------------------------------------
// Fused residual + LayerNorm: out = LN(hin + dlt)*g + b. dlt is bf16
// (out-proj/ff2 emit bf16) -> packed uint loads; thread handles elems 2t,2t+1.
// ---------------------------------------------------------------------------
__global__ __launch_bounds__(256) void ln_fused(const float* __restrict__ hin,
                                                const unsigned short* __restrict__ dlt,
                                                const float* __restrict__ g,
                                                const float* __restrict__ b,
                                                float* __restrict__ out,
                                                unsigned short* __restrict__ outb)
{
    __shared__ float red[256];
    const int r = blockIdx.x, t = threadIdx.x;
    const size_t base = (size_t)r * DD;
    float2 hv = *(const float2*)(hin + base + 2 * t);
    unsigned int dv = *(const unsigned int*)(dlt + base + 2 * t);
    float v0 = hv.x + bf2f((unsigned short)(dv & 0xffffu));
    float v1 = hv.y + bf2f((unsigned short)(dv >> 16));
    red[t] = v0 + v1;
    __syncthreads();
    for (int off = 128; off > 0; off >>= 1) { if (t < off) red[t] += red[t + off]; __syncthreads(); }
    float mu = red[0] * (1.f / 512.f);
    __syncthreads();
    float d0 = v0 - mu, d1 = v1 - mu;
    red[t] = d0 * d0 + d1 * d1;
    __syncthreads();
    for (int off = 128; off > 0; off >>= 1) { if (t < off) red[t] += red[t + off]; __syncthreads(); }
    float rs = rsqrtf(red[0] * (1.f / 512.f) + 1e-5f);
    float2 gv = *(const float2*)(g + 2 * t);
    float2 bv = *(const float2*)(b + 2 * t);
    float o0 = d0 * rs * gv.x + bv.x;
    float o1 = d1 * rs * gv.y + bv.y;
    float2 ov; ov.x = o0; ov.y = o1;
    *(float2*)(out + base + 2 * t) = ov;
    if (outb) {
        unsigned int pk = (unsigned int)f2bf(o0) | ((unsigned int)f2bf(o1) << 16);
        *(unsigned int*)(outb + base + 2 * t) = pk;
    }
}

// ---------------------------------------------------------------------------
extern "C" void kernel_launch(void* const* d_in, const int* in_sizes, int n_in,
                              void* d_out, int out_size, void* d_ws, size_t ws_size,
                              hipStream_t stream)
{
    (void)in_sizes; (void)n_in; (void)out_size; (void)ws_size;

    const float* x        = (const float*)d_in[0];
    const int*   ei       = (const int*)  d_in[1];
    const float* lin_w    = (const float*)d_in[3];
    const float* att_src  = (const float*)d_in[4];
    const float* att_dst  = (const float*)d_in[5];
    const float* gat_bias = (const float*)d_in[6];
    const float* qkv_w    = (const float*)d_in[7];
    const float* qkv_b    = (const float*)d_in[8];
    const float* out_w    = (const float*)d_in[9];
    const float* out_b    = (const float*)d_in[10];
    const float* ln1_g    = (const float*)d_in[11];
    const float* ln1_b    = (const float*)d_in[12];
    const float* ff1_w    = (const float*)d_in[13];
    const float* ff1_b    = (const float*)d_in[14];
    const float* ff2_w    = (const float*)d_in[15];
    const float* ff2_b    = (const float*)d_in[16];
    const float* ln2_g    = (const float*)d_in[17];
    const float* ln2_b    = (const float*)d_in[18];

    char* wsb = (char*)d_ws;
    size_t o = 0;
    auto alloc = [&](size_t bytes) { char* p = wsb + o; o += (bytes + 255) & ~(size_t)255; return p; };

    unsigned short* hlin_bf = (unsigned short*)alloc((size_t)NN * DD * 2);
    unsigned short* hbf     = (unsigned short*)alloc((size_t)NN * DD * 2);
    unsigned short* qkv16   = (unsigned short*)alloc((size_t)NN * D3 * 2);
    unsigned short* aob     = (unsigned short*)alloc((size_t)NN * DD * 2);
    unsigned short* ff1obf  = (unsigned short*)alloc((size_t)NN * DFF2 * 2);
    unsigned short* dltbf   = (unsigned short*)alloc((size_t)NN * DD * 2);
    float* hcur  = (float*)alloc((size_t)NN * DD * 4);
    float* a_src = (float*)alloc((size_t)NN * HH * 4);
    float* a_dst = (float*)alloc((size_t)NN * HH * 4);
    int* counts     = (int*)alloc(NN * 4);
    int* cursor     = (int*)alloc(NN * 4);
    int* offsets    = (int*)alloc((NN + 1) * 4);
    int* src_sorted = (int*)alloc(ENE * 4);
    unsigned short* xbf    = (unsigned short*)alloc((size_t)NN * IND * 2);
    unsigned short* linwbf = (unsigned short*)alloc((size_t)DD * IND * 2);
    unsigned short* qkvwbf = (unsigned short*)alloc((size_t)2 * D3 * DD * 2);
    unsigned short* outwbf = (unsigned short*)alloc((size_t)2 * DD * DD * 2);
    unsigned short* ff1wbf = (unsigned short*)alloc((size_t)2 * DFF2 * DD * 2);
    unsigned short* ff2wbf = (unsigned short*)alloc((size_t)2 * DD * DFF2 * 2);

    // --- weight/x conversion to bf16 (one pass) ---
    CvtJobs jb;
    jb.src[0] = x;      jb.dst[0] = xbf;    jb.n[0] = NN * IND;
    jb.src[1] = lin_w;  jb.dst[1] = linwbf; jb.n[1] = DD * IND;
    jb.src[2] = qkv_w;  jb.dst[2] = qkvwbf; jb.n[2] = 2 * D3 * DD;
    jb.src[3] = out_w;  jb.dst[3] = outwbf; jb.n[3] = 2 * DD * DD;
    jb.src[4] = ff1_w;  jb.dst[4] = ff1wbf; jb.n[4] = 2 * DFF2 * DD;
    jb.src[5] = ff2_w;  jb.dst[5] = ff2wbf; jb.n[5] = 2 * DD * DFF2;
    int cvt_total = jb.n[0]+jb.n[1]+jb.n[2]+jb.n[3]+jb.n[4]+jb.n[5];
    cvt_many<<<(cvt_total/4 + 255)/256, 256, 0, stream>>>(jb, cvt_total);

    // --- GAT ---
    hipMemsetAsync(counts, 0, 2 * NN * sizeof(int), stream);  // counts + cursor (adjacent)
    gemm64<<<dim3(DD/64, NN/64), 256, 0, stream>>>(xbf, linwbf, nullptr, hlin_bf,
                                                   NN, IND, DD, 1);
    att_proj<<<(NN*HH + 255)/256, 256, 0, stream>>>(hlin_bf, att_src, att_dst, a_src, a_dst);
    hist_kernel<<<(ENE + 255)/256, 256, 0, stream>>>(ei, counts);
    scan_kernel<<<1, 1024, 0, stream>>>(counts, offsets);
    scatter_kernel<<<(ENE + 255)/256, 256, 0, stream>>>(ei, offsets, cursor, src_sorted);
    gat_node<<<NN, 256, 0, stream>>>(hlin_bf, a_src, a_dst, offsets, src_sorted, gat_bias,
                                     hcur, hbf);

    // --- 2 transformer encoder layers (post-norm) ---
    for (int i = 0; i < 2; ++i) {
        gemm64<<<dim3(D3/64, NN/64), 256, 0, stream>>>(hbf, qkvwbf + (size_t)i*D3*DD,
                                                       qkv_b + (size_t)i*D3, qkv16,
                                                       NN, DD, D3, 1 | 4);
        attn_mfma<<<dim3(NN/64 * HH), 256, 0, stream>>>(qkv16, aob);
        gemm64<<<dim3(DD/64, NN/64), 256, 0, stream>>>(aob, outwbf + (size_t)i*DD*DD,
                                                       out_b + (size_t)i*DD, dltbf,
                                                       NN, DD, DD, 1);
        ln_fused<<<NN, 256, 0, stream>>>(hcur, dltbf, ln1_g + (size_t)i*DD, ln1_b + (size_t)i*DD,
                                         hcur, hbf);
        gemm64<<<dim3(DFF2/64, NN/64), 256, 0, stream>>>(hbf, ff1wbf + (size_t)i*DFF2*DD,
                                                         ff1_b + (size_t)i*DFF2, ff1obf,
                                                         NN, DD, DFF2, 1 | 2);
        gemm64<<<dim3(DD/64, NN/64), 256, 0, stream>>>(ff1obf, ff2wbf + (size_t)i*DD*DFF2,
                                                       ff2_b + (size_t)i*DD, dltbf,
                                                       NN, DFF2, DD, 1);
        float* outp = (i == 1) ? (float*)d_out : hcur;
        unsigned short* outbp = (i == 1) ? nullptr : hbf;
        ln_fused<<<NN, 256, 0, stream>>>(hcur, dltbf, ln2_g + (size_t)i*DD, ln2_b + (size_t)i*DD,
                                         outp, outbp);
    }
}